// Round 8
// baseline (363.875 us; speedup 1.0000x reference)
//
#include <hip/hip_runtime.h>

#define EE 512
#define HH 256
#define QQ 1024
#define SS 512
#define NSTEPS 3
#define NBLK 256

// ---------------------------------------------------------------------------
// Coherence protocol (R6+R7 post-mortem): NO cache-maintenance fences at all
// (each buffer_inv/wbl2 walk ~7-10us; 12 barriers made that ~90us). Kernel-
// written intermediates: sc1 write-through stores + sc1 loads (LLC coherence
// point). The R6 sc1-load tax is fixed STRUCTURALLY: streaming, wide, deep-
// pipelined sc1 access patterns (full-tile LDS staging; 8-16 loads in
// flight), never per-use scalar re-reads. Weights/inputs: plain cached loads,
// L2-hot across all phases since nothing ever invalidates L2.
// ---------------------------------------------------------------------------
__device__ __forceinline__ float ldc(const float* p) {
    return __hip_atomic_load(p, __ATOMIC_RELAXED, __HIP_MEMORY_SCOPE_AGENT);
}
__device__ __forceinline__ int ldci(const int* p) {
    return __hip_atomic_load(p, __ATOMIC_RELAXED, __HIP_MEMORY_SCOPE_AGENT);
}
__device__ __forceinline__ float2 ldc2(const float* p) {   // 8B sc1 load
    unsigned long long v = __hip_atomic_load(
        (const unsigned long long*)p, __ATOMIC_RELAXED,
        __HIP_MEMORY_SCOPE_AGENT);
    float2 r;
    r.x = __uint_as_float((unsigned)v);
    r.y = __uint_as_float((unsigned)(v >> 32));
    return r;
}
__device__ __forceinline__ void stc(float* p, float v) {
    __hip_atomic_store(p, v, __ATOMIC_RELAXED, __HIP_MEMORY_SCOPE_AGENT);
}
__device__ __forceinline__ void stci(int* p, int v) {
    __hip_atomic_store(p, v, __ATOMIC_RELAXED, __HIP_MEMORY_SCOPE_AGENT);
}
__device__ __forceinline__ void stc2(float* p, float x, float y) {
    unsigned long long v = ((unsigned long long)__float_as_uint(y) << 32)
                         | (unsigned long long)__float_as_uint(x);
    __hip_atomic_store((unsigned long long*)p, v, __ATOMIC_RELAXED,
                       __HIP_MEMORY_SCOPE_AGENT);
}
__device__ __forceinline__ void stc4(float* p, float4 o) {
    stc2(p + 0, o.x, o.y);
    stc2(p + 2, o.z, o.w);
}

// ---------------------------------------------------------------------------
// Fence-free grid barrier (R6's, measured cheap): entry __syncthreads drains
// each thread's vmcnt so all sc1 stores are at the LLC; arrival fetch_add +
// relaxed poll; ping-pong counters. No release/acquire walks.
// 256 blocks = 1/CU guaranteed resident (58KB LDS < 160KB/CU).
// ---------------------------------------------------------------------------
__device__ __forceinline__ void gbar(unsigned int* bar, unsigned int* gen) {
    __syncthreads();                       // drains vmcnt: sc1 stores at LLC
    if (threadIdx.x == 0) {
        const unsigned int g = *gen;
        unsigned int* cnt = &bar[32 + ((g & 1u) << 5)];
        unsigned int arrived = __hip_atomic_fetch_add(
            cnt, 1u, __ATOMIC_RELAXED, __HIP_MEMORY_SCOPE_AGENT);
        if (arrived == NBLK - 1u) {
            __hip_atomic_store(cnt, 0u, __ATOMIC_RELAXED,
                               __HIP_MEMORY_SCOPE_AGENT);
            asm volatile("s_waitcnt vmcnt(0)" ::: "memory"); // reset lands 1st
            __hip_atomic_store(&bar[0], g + 1u, __ATOMIC_RELAXED,
                               __HIP_MEMORY_SCOPE_AGENT);
        } else {
            while (__hip_atomic_load(&bar[0], __ATOMIC_RELAXED,
                                     __HIP_MEMORY_SCOPE_AGENT) < g + 1u) {
                __builtin_amdgcn_s_sleep(2);
            }
        }
        *gen = g + 1u;
    }
    __syncthreads();
}

// ---------------------------------------------------------------------------
// enc1 tile engine (inputs are read-only -> plain cached loads), K=EE=512.
// X-tile K-MAJOR (Xs[k][m], stride 66); register-prefetch double buffering.
// ---------------------------------------------------------------------------
__device__ __forceinline__ void mm_tile_in(const float* __restrict__ Xrow,
                                           const float* __restrict__ Wcol,
                                           float (*Xs)[66], float (*Ws)[68],
                                           float acc[2][4]) {
    const int tid = threadIdx.x;
    const int r   = tid >> 3;
    const int c4  = (tid & 7) << 2;
    const int c8  = (tid & 7) << 3;
    const int tx  = tid & 15;
    const int ty2 = (tid >> 4) << 1;

    float4 vx  = *(const float4*)&Xrow[r * EE + c4];
    float4 vw0 = *(const float4*)&Wcol[r * HH + c8];
    float4 vw1 = *(const float4*)&Wcol[r * HH + c8 + 4];

    for (int k0 = 0; k0 < EE; k0 += 32) {
        Xs[c4 + 0][r] = vx.x;
        Xs[c4 + 1][r] = vx.y;
        Xs[c4 + 2][r] = vx.z;
        Xs[c4 + 3][r] = vx.w;
        *(float4*)&Ws[r][c8]     = vw0;
        *(float4*)&Ws[r][c8 + 4] = vw1;
        __syncthreads();
        if (k0 + 32 < EE) {
            vx  = *(const float4*)&Xrow[r * EE + k0 + 32 + c4];
            vw0 = *(const float4*)&Wcol[(k0 + 32 + r) * HH + c8];
            vw1 = *(const float4*)&Wcol[(k0 + 32 + r) * HH + c8 + 4];
        }
        #pragma unroll
        for (int kk = 0; kk < 32; kk++) {
            float4 b = *(const float4*)&Ws[kk][tx << 2];
            float2 a = *(const float2*)&Xs[kk][ty2];
            acc[0][0] += a.x * b.x; acc[0][1] += a.x * b.y;
            acc[0][2] += a.x * b.z; acc[0][3] += a.x * b.w;
            acc[1][0] += a.y * b.x; acc[1][1] += a.y * b.y;
            acc[1][2] += a.y * b.z; acc[1][3] += a.y * b.w;
        }
        __syncthreads();
    }
}

// ---------------------------------------------------------------------------
// Intermediate-X tile engine, K=HH=256. X (kernel-written) is staged ONCE
// into k-major LDS via 16 in-flight 64-bit sc1 loads per thread (~1 LLC
// round-trip total), then the k-loop touches only LDS + plain-cached W.
// This removes R6's per-k-iter scalar sc1 X re-loads entirely.
// ---------------------------------------------------------------------------
__device__ __forceinline__ void mm_tile_c(const float* __restrict__ Xrow,
                                          const float* __restrict__ Wcol,
                                          float (*XsF)[33], float (*Ws)[68],
                                          float acc[2][4]) {
    const int tid = threadIdx.x;
    const int r   = tid >> 3;          // 0..31 (X row)
    const int kb  = (tid & 7) << 5;    // k-chunk base: 0,32,..,224
    const int c8  = (tid & 7) << 3;
    const int tx  = tid & 15;
    const int ty2 = (tid >> 4) << 1;

    // ---- full X-tile stage: 16 sc1 loads in flight, then LDS scatter ----
    float2 vv[16];
    #pragma unroll
    for (int u = 0; u < 16; u++)
        vv[u] = ldc2(&Xrow[r * HH + kb + (u << 1)]);
    #pragma unroll
    for (int u = 0; u < 16; u++) {
        XsF[kb + (u << 1) + 0][r] = vv[u].x;
        XsF[kb + (u << 1) + 1][r] = vv[u].y;
    }

    float4 vw0 = *(const float4*)&Wcol[r * HH + c8];
    float4 vw1 = *(const float4*)&Wcol[r * HH + c8 + 4];

    for (int k0 = 0; k0 < HH; k0 += 32) {
        *(float4*)&Ws[r][c8]     = vw0;
        *(float4*)&Ws[r][c8 + 4] = vw1;
        __syncthreads();
        if (k0 + 32 < HH) {
            vw0 = *(const float4*)&Wcol[(k0 + 32 + r) * HH + c8];
            vw1 = *(const float4*)&Wcol[(k0 + 32 + r) * HH + c8 + 4];
        }
        #pragma unroll
        for (int kk = 0; kk < 32; kk++) {
            float4 b = *(const float4*)&Ws[kk][tx << 2];
            float2 a = *(const float2*)&XsF[k0 + kk][ty2];
            acc[0][0] += a.x * b.x; acc[0][1] += a.x * b.y;
            acc[0][2] += a.x * b.z; acc[0][3] += a.x * b.w;
            acc[1][0] += a.y * b.x; acc[1][1] += a.y * b.y;
            acc[1][2] += a.y * b.z; acc[1][3] += a.y * b.w;
        }
        __syncthreads();
    }
}

struct KArgs {
    const float* qf;  const float* sf;  const int* y;
    const float* Wn1; const float* bn1; const float* Wn2; const float* bn2;
    const float* Wm1; const float* bm1; const float* Wm2; const float* bm2;
    const float* Wr1; const float* br1; const float* wr2; const float* br2;
    float* out; float* ws;
};

// ---------------------------------------------------------------------------
// Single persistent kernel, 256 blocks x 256 threads (1/CU). Phases:
//  P0 enc1(192 tiles)+stats | P1 enc2(192) |
//  [ab(128)+hq(128,t==0) | hsum(256x2) | gagg(64)] x3 | hsT(64) | scores(256x2)
// sc1 stores + streaming sc1 loads for intermediates; plain loads for
// weights/inputs; fence-free barriers.
// ---------------------------------------------------------------------------
__global__ __launch_bounds__(256) void fused_k(KArgs a) {
    __shared__ float Xs[32][66];       // enc1 X staging (K=512 path)
    __shared__ float XsF[HH][33];      // full X tile, K=256 path
    __shared__ float Ws[32][68];
    __shared__ int   lst[SS];
    __shared__ int   info[2];
    __shared__ int   lc[16];
    __shared__ float hqs[4][HH];
    __shared__ float w2s[HH];

    float* F    = a.ws;
    float* X1   = F + 0;             // 1536*256 (dead after enc2)
    float* QS   = F + 393216;        // 1536*256
    float* q    = QS;                // 1024*256
    float* s    = QS + QQ * HH;      // 512*256
    float* A    = F + 786432;        // 512*256
    float* Bm   = F + 917504;        // 512*256
    float* hsum = F + 1048576;       // 512*256
    float* hq   = F + 0;             // 1024*256 (reuses dead X1)
    float* hsT  = F + 262144;        // 256*512  (inside dead X1)
    float* cntf = F + 1179648;       // 512
    float* invd = F + 1180160;       // 512
    int*  icls  = (int*)(F + 1180672);
    int*  cls_cnt  = icls;           // 16
    int*  cls_list = icls + 16;      // 16*512
    unsigned int* bar = (unsigned int*)(F + 1200128);  // zeroed by host memset

    const int tid = threadIdx.x;
    const int bid = blockIdx.x;
    const int tx  = tid & 15, ty2 = (tid >> 4) << 1;
    unsigned int gen = 0;

    // ---------------- P0: enc1 (relu(x@Wn1+bn1)) + mask statistics ---------
    if (bid < 192) {
        const int m0 = (bid >> 2) << 5;
        const int n0 = (bid & 3) << 6;
        const float* Xrow = (m0 < QQ) ? (a.qf + m0 * EE) : (a.sf + (m0 - QQ) * EE);
        float acc[2][4] = {{0,0,0,0},{0,0,0,0}};
        mm_tile_in(Xrow, a.Wn1 + n0, Xs, Ws, acc);
        #pragma unroll
        for (int rr = 0; rr < 2; rr++) {
            int m = m0 + ty2 + rr;
            int n = n0 + (tx << 2);
            float4 o;
            o.x = fmaxf(acc[rr][0] + a.bn1[n + 0], 0.f);
            o.y = fmaxf(acc[rr][1] + a.bn1[n + 1], 0.f);
            o.z = fmaxf(acc[rr][2] + a.bn1[n + 2], 0.f);
            o.w = fmaxf(acc[rr][3] + a.bn1[n + 3], 0.f);
            stc4(&X1[m * HH + n], o);
        }
    } else if (bid == 192) {
        if (tid < 16) lc[tid] = 0;
        __syncthreads();
        for (int i = tid; i < SS; i += 256) {
            int c = a.y[i];
            int slot = atomicAdd(&lc[c], 1);
            stci(&cls_list[c * SS + slot], i);
        }
        __syncthreads();
        if (tid < 16) stci(&cls_cnt[tid], lc[tid]);
        for (int i = tid; i < SS; i += 256) {
            float n = (float)(lc[a.y[i]] - 1);
            stc(&cntf[i], n);
            stc(&invd[i], 1.f / fmaxf(n, 1.f));
        }
    }
    gbar(bar, &gen);

    // ---------------- P1: enc2 (X1@Wn2+bn2) -> QS --------------------------
    if (bid < 192) {
        const int m0 = (bid >> 2) << 5;
        const int n0 = (bid & 3) << 6;
        float acc[2][4] = {{0,0,0,0},{0,0,0,0}};
        mm_tile_c(X1 + m0 * HH, a.Wn2 + n0, XsF, Ws, acc);
        #pragma unroll
        for (int rr = 0; rr < 2; rr++) {
            int m = m0 + ty2 + rr;
            int n = n0 + (tx << 2);
            float4 o;
            o.x = acc[rr][0] + a.bn2[n + 0];
            o.y = acc[rr][1] + a.bn2[n + 1];
            o.z = acc[rr][2] + a.bn2[n + 2];
            o.w = acc[rr][3] + a.bn2[n + 3];
            stc4(&QS[m * HH + n], o);
        }
    }
    gbar(bar, &gen);

    // ---------------- message passing --------------------------------------
    for (int t = 0; t < NSTEPS; t++) {
        const float* W1t = a.Wm1 + t * 2 * HH * HH;
        const float* b1t = a.bm1 + t * HH;
        const float* W2t = a.Wm2 + t * HH * HH;
        const float* b2t = a.bm2 + t * HH;

        // ab: A = s@W1a, B = s@W1b  (+ hq = q@Wr1a co-scheduled at t==0)
        if (bid < 128) {
            int nt = bid & 7;
            const int m0 = (bid >> 3) << 5;
            const float* W = W1t;
            float* C = A;
            if (nt >= 4) { nt -= 4; W = W1t + HH * HH; C = Bm; }
            const int n0 = nt << 6;
            float acc[2][4] = {{0,0,0,0},{0,0,0,0}};
            mm_tile_c(s + m0 * HH, W + n0, XsF, Ws, acc);
            #pragma unroll
            for (int rr = 0; rr < 2; rr++) {
                int m = m0 + ty2 + rr;
                int n = n0 + (tx << 2);
                float4 o = { acc[rr][0], acc[rr][1], acc[rr][2], acc[rr][3] };
                stc4(&C[m * HH + n], o);
            }
        } else if (t == 0) {
            const int idx = bid - 128;        // 0..127
            const int m0 = (idx >> 2) << 5;
            const int n0 = (idx & 3) << 6;
            float acc[2][4] = {{0,0,0,0},{0,0,0,0}};
            mm_tile_c(q + m0 * HH, a.Wr1 + n0, XsF, Ws, acc);
            #pragma unroll
            for (int rr = 0; rr < 2; rr++) {
                int m = m0 + ty2 + rr;
                int n = n0 + (tx << 2);
                float4 o = { acc[rr][0], acc[rr][1], acc[rr][2], acc[rr][3] };
                stc4(&hq[m * HH + n], o);
            }
        }
        gbar(bar, &gen);

        // hsum: 2 support rows per block (bid, bid+256); 8-deep sc1 prefetch
        #pragma unroll
        for (int rep = 0; rep < 2; rep++) {
            const int i = bid + (rep << 8);
            const int h = tid;
            __syncthreads();                 // protect info/lst rewrite
            if (h == 0) { int yi = a.y[i]; info[0] = yi; info[1] = ldci(&cls_cnt[yi]); }
            __syncthreads();
            const int cnt = info[1];
            const int* Lp = cls_list + info[0] * SS;
            for (int m = h; m < cnt; m += 256) lst[m] = ldci(&Lp[m]);
            __syncthreads();
            const float av = ldc(&A[i * HH + h]) + b1t[h];
            float acc = 0.f;
            int m = 0;
            for (; m + 8 <= cnt; m += 8) {          // 8 loads in flight
                float v[8];
                #pragma unroll
                for (int u = 0; u < 8; u++) v[u] = ldc(&Bm[lst[m + u] * HH + h]);
                #pragma unroll
                for (int u = 0; u < 8; u++) acc += fmaxf(av + v[u], 0.f);
            }
            for (; m < cnt; m++) acc += fmaxf(av + ldc(&Bm[lst[m] * HH + h]), 0.f);
            acc -= fmaxf(av + ldc(&Bm[i * HH + h]), 0.f);  // remove self term
            stc(&hsum[i * HH + h], acc);
        }
        gbar(bar, &gen);

        // gagg: s += (hsum@W2 + cnt*bm2) * invd
        if (bid < 64) {
            const int m0 = (bid >> 2) << 5;
            const int n0 = (bid & 3) << 6;
            float acc[2][4] = {{0,0,0,0},{0,0,0,0}};
            mm_tile_c(hsum + m0 * HH, W2t + n0, XsF, Ws, acc);
            #pragma unroll
            for (int rr = 0; rr < 2; rr++) {
                int m = m0 + ty2 + rr;
                int n = n0 + (tx << 2);
                float ci = ldc(&cntf[m]), di = ldc(&invd[m]);
                float* sp = &s[m * HH + n];
                float2 s01 = ldc2(sp), s23 = ldc2(sp + 2);
                float4 o;
                o.x = s01.x + (acc[rr][0] + ci * b2t[n + 0]) * di;
                o.y = s01.y + (acc[rr][1] + ci * b2t[n + 1]) * di;
                o.z = s23.x + (acc[rr][2] + ci * b2t[n + 2]) * di;
                o.w = s23.y + (acc[rr][3] + ci * b2t[n + 3]) * di;
                stc4(sp, o);
            }
        }
        gbar(bar, &gen);
    }

    // ---------------- hsT[h][j] = (s@Wr1b)[j][h] + br1[h] -------------------
    if (bid < 64) {
        const int m0 = (bid >> 2) << 5;
        const int n0 = (bid & 3) << 6;
        float acc[2][4] = {{0,0,0,0},{0,0,0,0}};
        mm_tile_c(s + m0 * HH, a.Wr1 + HH * HH + n0, XsF, Ws, acc);
        #pragma unroll
        for (int rr = 0; rr < 2; rr++) {
            int m = m0 + ty2 + rr;
            #pragma unroll
            for (int c = 0; c < 4; c++) {
                int n = n0 + (tx << 2) + c;
                stc(&hsT[n * SS + m], acc[rr][c] + a.br1[n]);
            }
        }
    }
    gbar(bar, &gen);

    // ---------------- scores: 4 hq rows per block, both j-halves -----------
    // hsT streamed via sc1 with software double-buffer (8 loads in flight).
    {
        const int i0 = bid << 2;
        w2s[tid] = a.wr2[tid];
        #pragma unroll
        for (int ii = 0; ii < 4; ii++) hqs[ii][tid] = ldc(&hq[(i0 + ii) * HH + tid]);
        __syncthreads();
        const float b2 = a.br2[0];
        #pragma unroll
        for (int jh = 0; jh < 2; jh++) {
            const int j = (jh << 8) + tid;
            float acc[4] = {0, 0, 0, 0};
            float vcur[8];
            #pragma unroll
            for (int u = 0; u < 8; u++) vcur[u] = ldc(&hsT[u * SS + j]);
            for (int h0 = 0; h0 < HH; h0 += 8) {
                float vnext[8];
                const bool more = (h0 + 8 < HH);
                if (more) {
                    #pragma unroll
                    for (int u = 0; u < 8; u++)
                        vnext[u] = ldc(&hsT[(h0 + 8 + u) * SS + j]);
                }
                float4 w0 = *(const float4*)&w2s[h0];
                float4 w1 = *(const float4*)&w2s[h0 + 4];
                #pragma unroll
                for (int ii = 0; ii < 4; ii++) {
                    float4 a0 = *(const float4*)&hqs[ii][h0];
                    float4 a1 = *(const float4*)&hqs[ii][h0 + 4];
                    acc[ii] += fmaxf(vcur[0] + a0.x, 0.f) * w0.x
                             + fmaxf(vcur[1] + a0.y, 0.f) * w0.y
                             + fmaxf(vcur[2] + a0.z, 0.f) * w0.z
                             + fmaxf(vcur[3] + a0.w, 0.f) * w0.w
                             + fmaxf(vcur[4] + a1.x, 0.f) * w1.x
                             + fmaxf(vcur[5] + a1.y, 0.f) * w1.y
                             + fmaxf(vcur[6] + a1.z, 0.f) * w1.z
                             + fmaxf(vcur[7] + a1.w, 0.f) * w1.w;
                }
                if (more) {
                    #pragma unroll
                    for (int u = 0; u < 8; u++) vcur[u] = vnext[u];
                }
            }
            #pragma unroll
            for (int ii = 0; ii < 4; ii++)
                a.out[(i0 + ii) * SS + j] = acc[ii] + b2;
        }
    }
}

extern "C" void kernel_launch(void* const* d_in, const int* in_sizes, int n_in,
                              void* d_out, int out_size, void* d_ws, size_t ws_size,
                              hipStream_t stream) {
    KArgs ka;
    ka.qf  = (const float*)d_in[0];
    ka.sf  = (const float*)d_in[1];
    ka.y   = (const int*)d_in[2];
    ka.Wn1 = (const float*)d_in[3];
    ka.bn1 = (const float*)d_in[4];
    ka.Wn2 = (const float*)d_in[5];
    ka.bn2 = (const float*)d_in[6];
    ka.Wm1 = (const float*)d_in[7];
    ka.bm1 = (const float*)d_in[8];
    ka.Wm2 = (const float*)d_in[9];
    ka.bm2 = (const float*)d_in[10];
    ka.Wr1 = (const float*)d_in[11];
    ka.br1 = (const float*)d_in[12];
    ka.wr2 = (const float*)d_in[13];
    ka.br2 = (const float*)d_in[14];
    ka.out = (float*)d_out;
    ka.ws  = (float*)d_ws;

    // zero the grid-barrier state (gen + ping-pong counters, 3 cache lines)
    hipMemsetAsync((char*)d_ws + 1200128u * sizeof(float), 0, 384, stream);

    fused_k<<<dim3(NBLK), dim3(256), 0, stream>>>(ka);
}